// Round 2
// baseline (107.722 us; speedup 1.0000x reference)
//
#include <hip/hip_runtime.h>
#include <math.h>

// Problem constants (hardcoded in the reference layer)
#define B_ROWS 32768
#define DIM    1024
#define NC     7
#define D4     (DIM/4)
#define RPB    64          // rows per block in the main pass
#define BLK    256

#define ALPHA_C   0.5f
#define LAMBDA2_C 0.5f

// ws layout (floats):
//  [0]          pair_dist
//  [1..7]       coef1[7]
//  [8..56]      coef2[49]  (row-major, diag = 0)
//  [64..7231]   featsum[7*1024]
//  [7232..7238] counts[7] (float)
#define WS_PD     0
#define WS_COEF1  1
#define WS_COEF2  8
#define WS_FSUM   64
#define WS_CNT    (64 + NC*DIM)

__device__ __forceinline__ float waveReduceSum(float v) {
#pragma unroll
    for (int o = 32; o > 0; o >>= 1) v += __shfl_xor(v, o, 64);
    return v;
}

// ---------------------------------------------------------------------------
// Kernel 0: centers-only prologue. 1 block.
//  - zeroes featsum + counts region of ws
//  - Gram matrix G (7x7), norms, coef1/coef2, pair_dist -> ws
// ---------------------------------------------------------------------------
__global__ __launch_bounds__(BLK)
void prep_kernel(const float4* __restrict__ centers4, float* __restrict__ ws) {
    __shared__ __align__(16) float cen[NC * DIM];
    __shared__ float G[NC * NC];
    const int tid = threadIdx.x;

    // zero the accumulation region (featsum + counts)
    for (int i = tid; i < NC * DIM + 8; i += BLK) ws[WS_FSUM + i] = 0.0f;

    // stage centers into LDS
    for (int i = tid; i < NC * D4; i += BLK) ((float4*)cen)[i] = centers4[i];
    __syncthreads();

    const int wid = tid >> 6, lane = tid & 63;
    // 28 unique (j<=m) pairs; wave w handles pairs w*7 .. w*7+6
#pragma unroll 1
    for (int k = 0; k < 7; ++k) {
        const int p = wid * 7 + k;
        // triangular decode p -> (j, m), j<=m
        int j = 0, q = p;
        while (q >= 7 - j) { q -= 7 - j; ++j; }
        const int m = j + q;

        float s = 0.0f;
#pragma unroll
        for (int c4 = 0; c4 < 4; ++c4) {
            const float4 a = *(const float4*)&cen[j * DIM + (lane + c4 * 64) * 4];
            const float4 b = *(const float4*)&cen[m * DIM + (lane + c4 * 64) * 4];
            s += a.x * b.x + a.y * b.y + a.z * b.z + a.w * b.w;
        }
        s = waveReduceSum(s);
        if (lane == 0) { G[j * 7 + m] = s; G[m * 7 + j] = s; }
    }
    __syncthreads();

    if (tid == 0) {
        float inv[7], sumInv = 0.0f;
#pragma unroll
        for (int j = 0; j < 7; ++j) {
            inv[j] = 1.0f / sqrtf(G[j * 7 + j]);
            sumInv += inv[j];
        }
        float pdsum = 0.0f;
#pragma unroll
        for (int j = 0; j < 7; ++j) {
            ws[WS_COEF1 + j] = inv[j] * (sumInv - inv[j]);
#pragma unroll
            for (int m = 0; m < 7; ++m) {
                if (m == j) { ws[WS_COEF2 + j * 7 + m] = 0.0f; continue; }
                const float g = G[j * 7 + m];
                pdsum += g * inv[j] * inv[m] + 1.0f;
                ws[WS_COEF2 + j * 7 + m] = g * inv[j] * inv[m] * inv[m] * inv[m];
            }
        }
        ws[WS_PD] = LAMBDA2_C * pdsum;
    }
}

// ---------------------------------------------------------------------------
// Kernel 1: main streaming pass over feats (128 MB), 512 blocks x 64 rows.
// Per-thread: 7 float4 REGISTER class accumulators (statically indexed via
// full unroll + cndmask select) -> no LDS RMW chain in the loop.
// Loads batched 8 rows at a time (8 outstanding dwordx4 per wave).
// Per-row ssq: one ds_write to part[row][tid]; block-reduced every 32 rows.
// Class-sum flush: 28 f32 hardware atomics per thread at block end.
// ---------------------------------------------------------------------------
__global__ __launch_bounds__(BLK)
void main_kernel(const float4* __restrict__ feats4,
                 const float*  __restrict__ labels,
                 const float4* __restrict__ centers4,
                 const float*  __restrict__ ws_ro,
                 float* __restrict__ featsum,
                 float* __restrict__ counts,
                 float* __restrict__ result) {
    __shared__ __align__(16) float cen[NC * DIM];   // 28 KB
    __shared__ float part[32 * 257];                // 32.9 KB, stride 257: conflict-free
    __shared__ float red[256];
    __shared__ int   lbls[RPB];

    const int tid  = threadIdx.x;
    const int row0 = blockIdx.x * RPB;

    // stage centers into LDS
    for (int i = tid; i < NC * D4; i += BLK) ((float4*)cen)[i] = centers4[i];

    // decode one-hot labels for this block's rows
    if (tid < RPB) {
        const float* lr = labels + (size_t)(row0 + tid) * NC;
        int l = 0;
#pragma unroll
        for (int j = 1; j < NC; ++j) l = (lr[j] > 0.5f) ? j : l;
        lbls[tid] = l;
    }
    __syncthreads();

    const float pd = ws_ro[WS_PD];

    // per-class row counts (threads 0..6, registers)
    float mycnt = 0.0f;
    if (tid < NC) {
        for (int r = 0; r < RPB; ++r) mycnt += (lbls[r] == tid) ? 1.0f : 0.0f;
    }

    // register class accumulators (all indexing static after unroll)
    float4 acc[NC];
#pragma unroll
    for (int c = 0; c < NC; ++c) acc[c] = make_float4(0.f, 0.f, 0.f, 0.f);

#pragma unroll 1
    for (int half = 0; half < 2; ++half) {
#pragma unroll 1
        for (int ch = 0; ch < 4; ++ch) {
            const int rbase = half * 32 + ch * 8;
            // batched loads: 8 outstanding 16B loads
            float4 x[8];
#pragma unroll
            for (int r = 0; r < 8; ++r)
                x[r] = feats4[(size_t)(row0 + rbase + r) * D4 + tid];
#pragma unroll
            for (int r = 0; r < 8; ++r) {
                const int lbl = lbls[rbase + r];                       // broadcast ds_read
                const float4 c4 = *(const float4*)&cen[lbl * DIM + tid * 4];
                const float dx = x[r].x - c4.x, dy = x[r].y - c4.y;
                const float dz = x[r].z - c4.z, dw = x[r].w - c4.w;
                const float ssq = fmaf(dx, dx, fmaf(dy, dy, fmaf(dz, dz, dw * dw)));
#pragma unroll
                for (int c = 0; c < NC; ++c) {
                    const float kc = (lbl == c) ? 1.0f : 0.0f;
                    acc[c].x = fmaf(kc, x[r].x, acc[c].x);
                    acc[c].y = fmaf(kc, x[r].y, acc[c].y);
                    acc[c].z = fmaf(kc, x[r].z, acc[c].z);
                    acc[c].w = fmaf(kc, x[r].w, acc[c].w);
                }
                part[(ch * 8 + r) * 257 + tid] = ssq;                  // conflict-free
            }
        }
        __syncthreads();
        // stage 1: 256 threads, each sums 32 contiguous columns of one row
        {
            const int row = tid & 31, sub = tid >> 5;
            float s = 0.0f;
#pragma unroll
            for (int j = 0; j < 32; ++j) s += part[row * 257 + sub * 32 + j];
            red[sub * 32 + row] = s;
        }
        __syncthreads();
        // stage 2: 32 threads finish 8 partials each and write result
        if (tid < 32) {
            float s = 0.0f;
#pragma unroll
            for (int sub = 0; sub < 8; ++sub) s += red[sub * 32 + tid];
            result[row0 + half * 32 + tid] = 0.5f * s + pd;
        }
        __syncthreads();   // before part[] reuse in next half
    }

    // flush register class sums to global (hardware f32 atomics)
#pragma unroll
    for (int c = 0; c < NC; ++c) {
        float* dst = &featsum[c * DIM + tid * 4];
        unsafeAtomicAdd(dst + 0, acc[c].x);
        unsafeAtomicAdd(dst + 1, acc[c].y);
        unsafeAtomicAdd(dst + 2, acc[c].z);
        unsafeAtomicAdd(dst + 3, acc[c].w);
    }
    if (tid < NC) unsafeAtomicAdd(&counts[tid], mycnt);
}

// ---------------------------------------------------------------------------
// Kernel 2: epilogue — new_centers (7x1024). One block per class.
// ---------------------------------------------------------------------------
__global__ __launch_bounds__(BLK)
void finish_kernel(const float4* __restrict__ centers4,
                   const float*  __restrict__ ws,
                   float4* __restrict__ outC) {
    const int c = blockIdx.x;
    const int t = threadIdx.x;

    const float cnt    = ws[WS_CNT + c];
    const float coef1  = ws[WS_COEF1 + c];
    const float rdenom = 1.0f / (cnt + 1.0f);
    const float KADD   = LAMBDA2_C / (float)(NC - 1);

    const float4 cen = centers4[c * D4 + t];
    const float4 fs  = ((const float4*)(ws + WS_FSUM))[c * D4 + t];

    float Tx = cen.x * coef1, Ty = cen.y * coef1, Tz = cen.z * coef1, Tw = cen.w * coef1;
#pragma unroll
    for (int m = 0; m < NC; ++m) {
        const float k2 = ws[WS_COEF2 + c * 7 + m];   // 0 on diagonal
        const float4 cm = centers4[m * D4 + t];
        Tx -= k2 * cm.x; Ty -= k2 * cm.y; Tz -= k2 * cm.z; Tw -= k2 * cm.w;
    }

    const float ox = cen.x - ALPHA_C * ((cnt * cen.x - fs.x) * rdenom) + KADD * Tx;
    const float oy = cen.y - ALPHA_C * ((cnt * cen.y - fs.y) * rdenom) + KADD * Ty;
    const float oz = cen.z - ALPHA_C * ((cnt * cen.z - fs.z) * rdenom) + KADD * Tz;
    const float ow = cen.w - ALPHA_C * ((cnt * cen.w - fs.w) * rdenom) + KADD * Tw;

    outC[c * D4 + t] = make_float4(ox, oy, oz, ow);
}

// ---------------------------------------------------------------------------
extern "C" void kernel_launch(void* const* d_in, const int* in_sizes, int n_in,
                              void* d_out, int out_size, void* d_ws, size_t ws_size,
                              hipStream_t stream) {
    const float* feats   = (const float*)d_in[0];   // (32768, 1024)
    const float* labels  = (const float*)d_in[1];   // (32768, 7) one-hot
    const float* centers = (const float*)d_in[2];   // (7, 1024)
    float* out = (float*)d_out;                     // [32768 result | 7168 new_centers]
    float* ws  = (float*)d_ws;

    prep_kernel<<<1, BLK, 0, stream>>>((const float4*)centers, ws);

    main_kernel<<<B_ROWS / RPB, BLK, 0, stream>>>(
        (const float4*)feats, labels, (const float4*)centers,
        ws, ws + WS_FSUM, ws + WS_CNT, out);

    finish_kernel<<<NC, BLK, 0, stream>>>(
        (const float4*)centers, ws, (float4*)(out + B_ROWS));
}

// Round 3
// 65.823 us; speedup vs baseline: 1.6365x; 1.6365x over previous
//
#include <hip/hip_runtime.h>
#include <math.h>

// Problem constants (hardcoded in the reference layer)
#define B_ROWS 32768
#define DIM    1024
#define NC     7
#define D4     (DIM/4)
#define RPB    32          // rows per block in the main pass
#define BLK    256

#define ALPHA_C   0.5f
#define LAMBDA2_C 0.5f

// ws layout (floats):
//  [0]          pair_dist
//  [1..7]       coef1[7]
//  [8..56]      coef2[49]  (row-major, diag = 0)
//  [64..7231]   featsum[7*1024]
//  [7232..7238] counts[7] (float)
#define WS_PD     0
#define WS_COEF1  1
#define WS_COEF2  8
#define WS_FSUM   64
#define WS_CNT    (64 + NC*DIM)

__device__ __forceinline__ float waveReduceSum(float v) {
#pragma unroll
    for (int o = 32; o > 0; o >>= 1) v += __shfl_xor(v, o, 64);
    return v;
}

// ---------------------------------------------------------------------------
// Kernel 0: centers-only prologue. 1 block.
// ---------------------------------------------------------------------------
__global__ __launch_bounds__(BLK)
void prep_kernel(const float4* __restrict__ centers4, float* __restrict__ ws) {
    __shared__ __align__(16) float cen[NC * DIM];
    __shared__ float G[NC * NC];
    const int tid = threadIdx.x;

    // zero the accumulation region (featsum + counts)
    for (int i = tid; i < NC * DIM + 8; i += BLK) ws[WS_FSUM + i] = 0.0f;

    // stage centers into LDS
    for (int i = tid; i < NC * D4; i += BLK) ((float4*)cen)[i] = centers4[i];
    __syncthreads();

    const int wid = tid >> 6, lane = tid & 63;
#pragma unroll 1
    for (int k = 0; k < 7; ++k) {
        const int p = wid * 7 + k;
        int j = 0, q = p;
        while (q >= 7 - j) { q -= 7 - j; ++j; }
        const int m = j + q;

        float s = 0.0f;
#pragma unroll
        for (int c4 = 0; c4 < 4; ++c4) {
            const float4 a = *(const float4*)&cen[j * DIM + (lane + c4 * 64) * 4];
            const float4 b = *(const float4*)&cen[m * DIM + (lane + c4 * 64) * 4];
            s += a.x * b.x + a.y * b.y + a.z * b.z + a.w * b.w;
        }
        s = waveReduceSum(s);
        if (lane == 0) { G[j * 7 + m] = s; G[m * 7 + j] = s; }
    }
    __syncthreads();

    if (tid == 0) {
        float inv[7], sumInv = 0.0f;
#pragma unroll
        for (int j = 0; j < 7; ++j) {
            inv[j] = 1.0f / sqrtf(G[j * 7 + j]);
            sumInv += inv[j];
        }
        float pdsum = 0.0f;
#pragma unroll
        for (int j = 0; j < 7; ++j) {
            ws[WS_COEF1 + j] = inv[j] * (sumInv - inv[j]);
#pragma unroll
            for (int m = 0; m < 7; ++m) {
                if (m == j) { ws[WS_COEF2 + j * 7 + m] = 0.0f; continue; }
                const float g = G[j * 7 + m];
                pdsum += g * inv[j] * inv[m] + 1.0f;
                ws[WS_COEF2 + j * 7 + m] = g * inv[j] * inv[m] * inv[m] * inv[m];
            }
        }
        ws[WS_PD] = LAMBDA2_C * pdsum;
    }
}

// ---------------------------------------------------------------------------
// Kernel 1: main streaming pass, 1024 blocks x 32 rows.
//  - register class accumulators (7 float4, statically indexed)
//  - 8-row load batches (8 outstanding dwordx4 per wave)
//  - ssq: 8 INTERLEAVED shfl-xor trees per batch, one 512B partial buffer
//  - flush: stage acc into the dead cen LDS, then lane-consecutive 4B atomics
//  - LDS ~29.3 KB -> 5 blocks/CU capacity; VGPR capped for 5 waves/EU
// ---------------------------------------------------------------------------
__global__ __launch_bounds__(BLK, 5)
void main_kernel(const float4* __restrict__ feats4,
                 const float*  __restrict__ labels,
                 const float4* __restrict__ centers4,
                 const float*  __restrict__ ws_ro,
                 float* __restrict__ featsum,
                 float* __restrict__ counts,
                 float* __restrict__ result) {
    __shared__ __align__(16) float cen[NC * DIM];   // 28 KB (reused for flush)
    __shared__ float partial[RPB * 4];              // 512 B
    __shared__ int   lbls[RPB];

    const int tid  = threadIdx.x;
    const int row0 = blockIdx.x * RPB;
    const int wid = tid >> 6, lane = tid & 63;

    // stage centers into LDS
    for (int i = tid; i < NC * D4; i += BLK) ((float4*)cen)[i] = centers4[i];

    // decode one-hot labels for this block's rows
    if (tid < RPB) {
        const float* lr = labels + (size_t)(row0 + tid) * NC;
        int l = 0;
#pragma unroll
        for (int j = 1; j < NC; ++j) l = (lr[j] > 0.5f) ? j : l;
        lbls[tid] = l;
    }
    __syncthreads();

    const float pd = ws_ro[WS_PD];

    // per-class row counts (threads 0..6, registers)
    float mycnt = 0.0f;
    if (tid < NC) {
        for (int r = 0; r < RPB; ++r) mycnt += (lbls[r] == tid) ? 1.0f : 0.0f;
    }

    // register class accumulators
    float4 acc[NC];
#pragma unroll
    for (int c = 0; c < NC; ++c) acc[c] = make_float4(0.f, 0.f, 0.f, 0.f);

    const float4* fp = feats4 + (size_t)row0 * D4 + tid;

#pragma unroll 1
    for (int ch = 0; ch < RPB / 8; ++ch) {
        const int rbase = ch * 8;
        // batched loads: 8 outstanding 16B loads
        float4 x[8];
#pragma unroll
        for (int r = 0; r < 8; ++r) x[r] = fp[(rbase + r) * D4];

        float ssq[8];
#pragma unroll
        for (int r = 0; r < 8; ++r) {
            const int lbl = lbls[rbase + r];                       // broadcast ds_read
            const float4 c4 = *(const float4*)&cen[lbl * DIM + tid * 4];
            const float dx = x[r].x - c4.x, dy = x[r].y - c4.y;
            const float dz = x[r].z - c4.z, dw = x[r].w - c4.w;
            ssq[r] = fmaf(dx, dx, fmaf(dy, dy, fmaf(dz, dz, dw * dw)));
#pragma unroll
            for (int c = 0; c < NC; ++c) {
                const float kc = (lbl == c) ? 1.0f : 0.0f;
                acc[c].x = fmaf(kc, x[r].x, acc[c].x);
                acc[c].y = fmaf(kc, x[r].y, acc[c].y);
                acc[c].z = fmaf(kc, x[r].z, acc[c].z);
                acc[c].w = fmaf(kc, x[r].w, acc[c].w);
            }
        }
        // 8 interleaved shfl-xor reduction trees (independent chains)
#pragma unroll
        for (int o = 32; o > 0; o >>= 1) {
#pragma unroll
            for (int r = 0; r < 8; ++r) ssq[r] += __shfl_xor(ssq[r], o, 64);
        }
        if (lane == 0) {
#pragma unroll
            for (int r = 0; r < 8; ++r) partial[(rbase + r) * 4 + wid] = ssq[r];
        }
    }
    __syncthreads();

    // finish per-row loss
    if (tid < RPB) {
        const float s = partial[tid * 4] + partial[tid * 4 + 1] +
                        partial[tid * 4 + 2] + partial[tid * 4 + 3];
        result[row0 + tid] = 0.5f * s + pd;
    }

    // stage register acc into (dead) cen LDS for a coalesced flush
    __syncthreads();   // everyone done reading cen
#pragma unroll
    for (int c = 0; c < NC; ++c)
        *(float4*)&cen[c * DIM + tid * 4] = acc[c];
    __syncthreads();

    // lane-consecutive 4B atomics (coalesced at L2/IF)
    for (int i = tid; i < NC * DIM; i += BLK) unsafeAtomicAdd(&featsum[i], cen[i]);
    if (tid < NC) unsafeAtomicAdd(&counts[tid], mycnt);
}

// ---------------------------------------------------------------------------
// Kernel 2: epilogue — new_centers (7x1024). One block per class.
// ---------------------------------------------------------------------------
__global__ __launch_bounds__(BLK)
void finish_kernel(const float4* __restrict__ centers4,
                   const float*  __restrict__ ws,
                   float4* __restrict__ outC) {
    const int c = blockIdx.x;
    const int t = threadIdx.x;

    const float cnt    = ws[WS_CNT + c];
    const float coef1  = ws[WS_COEF1 + c];
    const float rdenom = 1.0f / (cnt + 1.0f);
    const float KADD   = LAMBDA2_C / (float)(NC - 1);

    const float4 cen = centers4[c * D4 + t];
    const float4 fs  = ((const float4*)(ws + WS_FSUM))[c * D4 + t];

    float Tx = cen.x * coef1, Ty = cen.y * coef1, Tz = cen.z * coef1, Tw = cen.w * coef1;
#pragma unroll
    for (int m = 0; m < NC; ++m) {
        const float k2 = ws[WS_COEF2 + c * 7 + m];   // 0 on diagonal
        const float4 cm = centers4[m * D4 + t];
        Tx -= k2 * cm.x; Ty -= k2 * cm.y; Tz -= k2 * cm.z; Tw -= k2 * cm.w;
    }

    const float ox = cen.x - ALPHA_C * ((cnt * cen.x - fs.x) * rdenom) + KADD * Tx;
    const float oy = cen.y - ALPHA_C * ((cnt * cen.y - fs.y) * rdenom) + KADD * Ty;
    const float oz = cen.z - ALPHA_C * ((cnt * cen.z - fs.z) * rdenom) + KADD * Tz;
    const float ow = cen.w - ALPHA_C * ((cnt * cen.w - fs.w) * rdenom) + KADD * Tw;

    outC[c * D4 + t] = make_float4(ox, oy, oz, ow);
}

// ---------------------------------------------------------------------------
extern "C" void kernel_launch(void* const* d_in, const int* in_sizes, int n_in,
                              void* d_out, int out_size, void* d_ws, size_t ws_size,
                              hipStream_t stream) {
    const float* feats   = (const float*)d_in[0];   // (32768, 1024)
    const float* labels  = (const float*)d_in[1];   // (32768, 7) one-hot
    const float* centers = (const float*)d_in[2];   // (7, 1024)
    float* out = (float*)d_out;                     // [32768 result | 7168 new_centers]
    float* ws  = (float*)d_ws;

    prep_kernel<<<1, BLK, 0, stream>>>((const float4*)centers, ws);

    main_kernel<<<B_ROWS / RPB, BLK, 0, stream>>>(
        (const float4*)feats, labels, (const float4*)centers,
        ws, ws + WS_FSUM, ws + WS_CNT, out);

    finish_kernel<<<NC, BLK, 0, stream>>>(
        (const float4*)centers, ws, (float4*)(out + B_ROWS));
}